// Round 15
// baseline (444.707 us; speedup 1.0000x reference)
//
#include <hip/hip_runtime.h>
#include <hip/hip_fp16.h>

// NCC loss: 9^3 box sums of {I, J, I*I, J*J, I*J}, per-voxel cc, -mean(cc).
// Dims: C=2, D=192, H=224, W=192, fp32.
//   P1 (k_dwt): march-D producer with round-11's proven step body. Thread
//     owns 4 px; 3 aligned float4 spans of I,J per slice (6 loads), BOTH the
//     add-slice (d+4) and drop-slice (d-4) spans prefetched one full step
//     ahead; rolling raw L/M/R float4 sums per field (add/psub with fmaf);
//     9-tap W window formed at output; fp16 stores to TRANSPOSED
//     [f][c][h][d][w]. Zero LDS / cross-lane / barriers.
//   P2 (k_hcc): proven consumer (r14, ~28us): marches H = outermost axis of
//     the transposed buffer; fp32 ring[5][9]; cc; block reduce.

#define C2   2
#define DDIM 192
#define HDIM 224
#define WDIM 192
#define HWN  (HDIM*WDIM)              // 43008
#define VOL  ((size_t)DDIM*HWN)       // 8257536 per input channel
#define PLN  (DDIM*WDIM)              // 36864 transposed inner (d,w) plane
#define RAD  4
#define WINV (1.0f/729.0f)

#define DS1  16   // P1 D-sub-chunk (192/16 = 12) -> 4032 waves = 3.9/SIMD
#define HS2  56   // P2 H-sub-chunk (224/56 = 4)

__device__ __forceinline__ float4 zero4() { float4 z; z.x=z.y=z.z=z.w=0.f; return z; }

__device__ __forceinline__ void padd(float4& r0, float4& r1, float4& r2,
                                     float4& r3, float4& r4,
                                     const float4 a, const float4 b) {
    r0.x+=a.x; r0.y+=a.y; r0.z+=a.z; r0.w+=a.w;
    r1.x+=b.x; r1.y+=b.y; r1.z+=b.z; r1.w+=b.w;
    r2.x=fmaf(a.x,a.x,r2.x); r2.y=fmaf(a.y,a.y,r2.y);
    r2.z=fmaf(a.z,a.z,r2.z); r2.w=fmaf(a.w,a.w,r2.w);
    r3.x=fmaf(b.x,b.x,r3.x); r3.y=fmaf(b.y,b.y,r3.y);
    r3.z=fmaf(b.z,b.z,r3.z); r3.w=fmaf(b.w,b.w,r3.w);
    r4.x=fmaf(a.x,b.x,r4.x); r4.y=fmaf(a.y,b.y,r4.y);
    r4.z=fmaf(a.z,b.z,r4.z); r4.w=fmaf(a.w,b.w,r4.w);
}
__device__ __forceinline__ void psub(float4& r0, float4& r1, float4& r2,
                                     float4& r3, float4& r4,
                                     const float4 a, const float4 b) {
    r0.x-=a.x; r0.y-=a.y; r0.z-=a.z; r0.w-=a.w;
    r1.x-=b.x; r1.y-=b.y; r1.z-=b.z; r1.w-=b.w;
    r2.x=fmaf(-a.x,a.x,r2.x); r2.y=fmaf(-a.y,a.y,r2.y);
    r2.z=fmaf(-a.z,a.z,r2.z); r2.w=fmaf(-a.w,a.w,r2.w);
    r3.x=fmaf(-b.x,b.x,r3.x); r3.y=fmaf(-b.y,b.y,r3.y);
    r3.z=fmaf(-b.z,b.z,r3.z); r3.w=fmaf(-b.w,b.w,r3.w);
    r4.x=fmaf(-a.x,b.x,r4.x); r4.y=fmaf(-a.y,b.y,r4.y);
    r4.z=fmaf(-a.z,b.z,r4.z); r4.w=fmaf(-a.w,b.w,r4.w);
}

// ---------------- P1: W-sum spans + D-roll, march D, transposed store ----------------
// grid: (HDIM/4, DDIM/DS1, C2); block 192 = 4 h-rows x 48 threads (4 px each)
// out layout (fp16): [f][c][h][d][w]
__global__ __launch_bounds__(192, 4)
void k_dwt(const float* __restrict__ I, const float* __restrict__ J,
           __half* __restrict__ buf)
{
    const int tid = threadIdx.x;
    const int r   = tid / 48;          // h-row within block
    const int k   = tid % 48;          // w-group
    const int w0  = 4*k;
    const int h   = (int)blockIdx.x*4 + r;
    const int c   = (int)blockIdx.z;
    const int ds0 = (int)blockIdx.y*DS1;
    const bool le = (k == 0), re = (k == 47);

    const float* __restrict__ Ib = I + (size_t)c*VOL + (size_t)h*WDIM + w0;
    const float* __restrict__ Jb = J + (size_t)c*VOL + (size_t)h*WDIM + w0;

    // rolling D-window sums over spans L=[w0-4..w0-1] M=[w0..w0+3] R=[w0+4..w0+7]
    float4 L0=zero4(),L1=zero4(),L2=zero4(),L3=zero4(),L4=zero4();
    float4 M0=zero4(),M1=zero4(),M2=zero4(),M3=zero4(),M4=zero4();
    float4 R0=zero4(),R1=zero4(),R2=zero4(),R3=zero4(),R4=zero4();

    float4 aIL,aIM,aIR,aJL,aJM,aJR;   // prefetched add slice (d+4)
    float4 dIL,dIM,dIR,dJL,dJM,dJR;   // prefetched drop slice (d-4)

#define LOADSLICE(DD, OK, IL, IM, IR, JL, JM, JR) do {                        \
    IL = zero4(); IM = zero4(); IR = zero4();                                 \
    JL = zero4(); JM = zero4(); JR = zero4();                                 \
    if (OK) {                                                                 \
        const float* ri = Ib + (size_t)(DD)*HWN;                              \
        const float* rj = Jb + (size_t)(DD)*HWN;                              \
        IM = *(const float4*)ri;  JM = *(const float4*)rj;                    \
        if (!le) { IL = *(const float4*)(ri-4); JL = *(const float4*)(rj-4); }\
        if (!re) { IR = *(const float4*)(ri+4); JR = *(const float4*)(rj+4); }\
    } } while (0)

    // warm-up: slices ds0-4 .. ds0+3 (zero padded below 0)
    for (int q = 0; q < 8; ++q) {
        const int dd = ds0 - RAD + q;
        LOADSLICE(dd, (dd >= 0), dIL,dIM,dIR,dJL,dJM,dJR);
        padd(L0,L1,L2,L3,L4, dIL, dJL);
        padd(M0,M1,M2,M3,M4, dIM, dJM);
        padd(R0,R1,R2,R3,R4, dIR, dJR);
    }
    // prefetch step-0 add slice (ds0+4 <= 180 < 192 always) and drop slice (ds0-4)
    LOADSLICE(ds0 + RAD, true, aIL,aIM,aIR,aJL,aJM,aJR);
    LOADSLICE(ds0 - RAD, (ds0 - RAD >= 0), dIL,dIM,dIR,dJL,dJM,dJR);

    // transposed output: field f, channel c, row h plane; slice d at d*WDIM
    __half* const ob = buf + ((size_t)c*HDIM + h)*PLN + w0;
    const size_t fstride = (size_t)C2*HDIM*PLN;

#define WST(F, LL, MM, RR) {                                                  \
    const float o0 = ((LL.x+LL.y)+(LL.z+LL.w))                                \
                   + ((MM.x+MM.y)+(MM.z+MM.w)) + RR.x;                        \
    const float o1 = o0 - LL.x + RR.y;                                        \
    const float o2 = o1 - LL.y + RR.z;                                        \
    const float o3 = o2 - LL.z + RR.w;                                        \
    uint2 u;                                                                  \
    u.x = __builtin_bit_cast(unsigned int, __floats2half2_rn(o0, o1));        \
    u.y = __builtin_bit_cast(unsigned int, __floats2half2_rn(o2, o3));        \
    *reinterpret_cast<uint2*>(ob + (size_t)(F)*fstride + (size_t)d*WDIM) = u; }

    for (int i = 0; i < DS1; ++i) {
        const int d = ds0 + i;
        // consume prefetched add slice (d+4)
        padd(L0,L1,L2,L3,L4, aIL, aJL);
        padd(M0,M1,M2,M3,M4, aIM, aJM);
        padd(R0,R1,R2,R3,R4, aIR, aJR);
        // hold drop slice values; then issue BOTH next-step prefetches
        const float4 hIL=dIL,hIM=dIM,hIR=dIR,hJL=dJL,hJM=dJM,hJR=dJR;
        {
            const int na = d + 1 + RAD;                    // next add slice
            LOADSLICE(na, (i + 1 < DS1) && (na < DDIM), aIL,aIM,aIR,aJL,aJM,aJR);
            const int nd = d + 1 - RAD;                    // next drop slice
            LOADSLICE(nd, (i + 1 < DS1) && (nd >= 0), dIL,dIM,dIR,dJL,dJM,dJR);
        }
        // window [d-4 .. d+4] ready -> emit 4 outputs per field (transposed)
        WST(0, L0, M0, R0) WST(1, L1, M1, R1) WST(2, L2, M2, R2)
        WST(3, L3, M3, R3) WST(4, L4, M4, R4)
        // drop slice d-4
        psub(L0,L1,L2,L3,L4, hIL, hJL);
        psub(M0,M1,M2,M3,M4, hIM, hJM);
        psub(R0,R1,R2,R3,R4, hIR, hJR);
    }
#undef WST
#undef LOADSLICE
}

// -------- P2: H-sum (register ring) + cc + block reduce — march outermost H --------
// grid: (PLN/256, HDIM/HS2, C2); block 256
__global__ __launch_bounds__(256)
void k_hcc(const __half* __restrict__ buf, double* __restrict__ gacc)
{
    const int tid = threadIdx.x;
    const int pix = blockIdx.x*256 + tid;      // (d,w) flat, PLN = 144*256 exact
    const int c   = blockIdx.z;
    const int hs0 = blockIdx.y*HS2;

    const size_t fstride = (size_t)C2*HDIM*PLN;
    const __half* base = buf + (size_t)c*HDIM*PLN + pix;

    float ring[5][9];
    float rs[5] = {0.f,0.f,0.f,0.f,0.f};
    float acc = 0.f;

    // warm-up: rows hs0-4 .. hs0+3
    #pragma unroll
    for (int q = 0; q < 8; ++q) {
        const int hh = hs0 - RAD + q;
        float v[5] = {0.f,0.f,0.f,0.f,0.f};
        if (hh >= 0) {
            const __half* pp = base + (size_t)hh*PLN;
            #pragma unroll
            for (int f = 0; f < 5; ++f) v[f] = __half2float(pp[(size_t)f*fstride]);
        }
        #pragma unroll
        for (int f = 0; f < 5; ++f) { ring[f][q] = v[f]; rs[f] += v[f]; }
    }

    int i = 0;
    while (i < HS2) {
        #pragma unroll
        for (int p = 0; p < 9; ++p) {   // i == p (mod 9) whenever body runs
            if (i < HS2) {
                const int hh = hs0 + i + RAD;
                float v[5] = {0.f,0.f,0.f,0.f,0.f};
                if (hh < HDIM) {
                    const __half* pp = base + (size_t)hh*PLN;
                    #pragma unroll
                    for (int f = 0; f < 5; ++f) v[f] = __half2float(pp[(size_t)f*fstride]);
                }
                float S[5];
                #pragma unroll
                for (int f = 0; f < 5; ++f) {
                    rs[f] += v[f];              // full 9x9x9 sum at row hs0+i
                    S[f] = rs[f];
                    rs[f] -= ring[f][p];        // drop row -8
                    ring[f][(p+8)%9] = v[f];    // keep row +4
                }
                const float uI    = S[0]*WINV;
                const float uJ    = S[1]*WINV;
                const float cross = S[4] - uJ*S[0];
                const float Iv    = S[2] - uI*S[0];
                const float Jv    = S[3] - uJ*S[1];
                acc += cross*cross / (Iv*Jv + 1e-5f);
                ++i;
            }
        }
    }

    // block reduction -> one double atomic per block
    __shared__ float wred[4];
    #pragma unroll
    for (int off = 32; off > 0; off >>= 1) acc += __shfl_down(acc, off);
    if ((tid & 63) == 0) wred[tid >> 6] = acc;
    __syncthreads();
    if (tid == 0) {
        const float sum = wred[0] + wred[1] + wred[2] + wred[3];
        atomicAdd(gacc, (double)sum);
    }
}

__global__ void k_fin(const double* __restrict__ gacc, float* __restrict__ out)
{
    out[0] = (float)(-gacc[0] / (double)((size_t)C2*DDIM*HDIM*WDIM));
}

extern "C" void kernel_launch(void* const* d_in, const int* in_sizes, int n_in,
                              void* d_out, int out_size, void* d_ws, size_t ws_size,
                              hipStream_t stream)
{
    if (n_in < 2) return;
    const float* I = (const float*)d_in[0];
    const float* J = (const float*)d_in[1];
    float* out = (float*)d_out;
    double* gacc = (double*)d_ws;
    __half* buf = (__half*)((char*)d_ws + 256);

    // transposed fp16 DW-summed fields: 5*2*224*36864*2 B = 165 MB
    const size_t need = 256 + (size_t)5*C2*HDIM*PLN*sizeof(__half);
    if (need > ws_size) return;

    hipMemsetAsync(d_ws, 0, 256, stream);   // zero the double accumulator

    dim3 g1(HDIM/4, DDIM/DS1, C2);           // 56 x 12 x 2 blocks
    k_dwt<<<g1, dim3(192,1,1), 0, stream>>>(I, J, buf);

    dim3 g2(PLN/256, HDIM/HS2, C2);          // 144 x 4 x 2 blocks
    k_hcc<<<g2, dim3(256,1,1), 0, stream>>>(buf, gacc);

    k_fin<<<1,1,0,stream>>>(gacc, out);
}

// Round 17
// 155.981 us; speedup vs baseline: 2.8510x; 2.8510x over previous
//
#include <hip/hip_runtime.h>
#include <hip/hip_fp16.h>

// NCC loss: 9^3 box sums of {I, J, I*I, J*J, I*J}, per-voxel cc, -mean(cc).
// Dims: C=2, D=192, H=224, W=192, fp32.
// Layout insight (rounds 1-15): kernels win iff the whole GPU advances a few
// DENSE sequential streams. Voxel-interleaved records [c][d][h][pair][5xhalf2]
// (20 B/pair) make the H-march consumer purely sequential per (c,d).
//   P1 (k_dwp): D-march producer (r12 shape, proven) + in-thread W-sum
//     (r14 spans). half2 ring along D (exact add/drop). Stores one 20-B
//     record per step -> wave writes 1280 B dense in planar slice order.
//   P2 (k_hcc2): H-march consumer over the interleaved buffer — sequential
//     reads, half2 ring along H, cc + block reduce. Writes nothing.
// r16 -> r17 fix: ring store slot must be (p9+8)%9, NOT p9 (slot-reuse read
// uninitialized slot 8 at step 8 -> NaN).

#define C2   2
#define DDIM 192
#define HDIM 224
#define WDIM 192
#define HWN  (HDIM*WDIM)              // 43008
#define VOL  ((size_t)DDIM*HWN)       // 8257536 per input channel
#define RAD  4
#define WINV (1.0f/729.0f)

#define RPW  96                        // records (w-pairs) per row
#define RH   10                        // halves per record (5 fields x 2 px)
#define ROWH (RPW*RH)                  // 960 halves per row
#define SLH  ((size_t)HDIM*ROWH)       // 215040 halves per (c,d) slice

#define DS1  24                        // P1 D-chunk (192/24 = 8)
#define HT2  28                        // P2 H-strip (224/28 = 8)

// ---------------- P1: W-sum (in-thread) + D-ring, march D, interleaved store ----------------
// grid: (21504/256, DDIM/DS1, C2); block 256; thread owns w-pair (2p, 2p+1) of row h
__global__ __launch_bounds__(256)
void k_dwp(const float* __restrict__ I, const float* __restrict__ J,
           __half* __restrict__ buf)
{
    const int tid = threadIdx.x;
    const int pr  = blockIdx.x*256 + tid;   // (h,p) flat: 224*96 = 21504
    const int h   = pr / RPW;
    const int p   = pr % RPW;
    const int w0  = 2*p;
    const int c   = blockIdx.z;
    const int ds0 = blockIdx.y*DS1;

    const bool mA = (p >= 2), mB = (p >= 1), mD = (p <= 94), mE = (p <= 93);

    const float* Ib = I + (size_t)c*VOL + (size_t)h*WDIM + w0;
    const float* Jb = J + (size_t)c*VOL + (size_t)h*WDIM + w0;

    // record base for (c, h, p); slice d at + d*SLH
    __half* const ob = buf + (size_t)c*DDIM*SLH + (size_t)h*ROWH + p*RH;

    __half2 ring[5][9];
    float2  rs[5];
    #pragma unroll
    for (int f = 0; f < 5; ++f) { rs[f].x = 0.f; rs[f].y = 0.f; }

    // per-slice 9-tap W-sums for the pair -> rounded half2 per field
#define WSLICE(DD, DOK, OUT)                                                  \
    {                                                                         \
        float iv[10], jv[10];                                                 \
        _Pragma("unroll") for (int t = 0; t < 10; ++t) { iv[t]=0.f; jv[t]=0.f; } \
        if (DOK) {                                                            \
            const float* ri = Ib + (size_t)(DD)*HWN;                          \
            const float* rj = Jb + (size_t)(DD)*HWN;                          \
            float2 v;                                                         \
            v = *(const float2*)(ri);     iv[4]=v.x; iv[5]=v.y;               \
            v = *(const float2*)(rj);     jv[4]=v.x; jv[5]=v.y;               \
            if (mA) { v = *(const float2*)(ri-4); iv[0]=v.x; iv[1]=v.y;       \
                      v = *(const float2*)(rj-4); jv[0]=v.x; jv[1]=v.y; }     \
            if (mB) { v = *(const float2*)(ri-2); iv[2]=v.x; iv[3]=v.y;       \
                      v = *(const float2*)(rj-2); jv[2]=v.x; jv[3]=v.y; }     \
            if (mD) { v = *(const float2*)(ri+2); iv[6]=v.x; iv[7]=v.y;       \
                      v = *(const float2*)(rj+2); jv[6]=v.x; jv[7]=v.y; }     \
            if (mE) { v = *(const float2*)(ri+4); iv[8]=v.x; iv[9]=v.y;       \
                      v = *(const float2*)(rj+4); jv[8]=v.x; jv[9]=v.y; }     \
        }                                                                     \
        float s8;                                                             \
        s8 = 0.f; _Pragma("unroll") for (int t=1;t<9;++t) s8 += iv[t];        \
        OUT[0] = __floats2half2_rn(s8+iv[0], s8+iv[9]);                       \
        s8 = 0.f; _Pragma("unroll") for (int t=1;t<9;++t) s8 += jv[t];        \
        OUT[1] = __floats2half2_rn(s8+jv[0], s8+jv[9]);                       \
        s8 = 0.f; _Pragma("unroll") for (int t=1;t<9;++t) s8 += iv[t]*iv[t];  \
        OUT[2] = __floats2half2_rn(s8+iv[0]*iv[0], s8+iv[9]*iv[9]);           \
        s8 = 0.f; _Pragma("unroll") for (int t=1;t<9;++t) s8 += jv[t]*jv[t];  \
        OUT[3] = __floats2half2_rn(s8+jv[0]*jv[0], s8+jv[9]*jv[9]);           \
        s8 = 0.f; _Pragma("unroll") for (int t=1;t<9;++t) s8 += iv[t]*jv[t];  \
        OUT[4] = __floats2half2_rn(s8+iv[0]*jv[0], s8+iv[9]*jv[9]);           \
    }

    // warm-up: slices ds0-4 .. ds0+3 fill ring slots 0..7
    #pragma unroll
    for (int q = 0; q < 8; ++q) {
        const int dd = ds0 - RAD + q;
        __half2 wsl[5];
        WSLICE(dd, (dd >= 0), wsl);
        #pragma unroll
        for (int f = 0; f < 5; ++f) {
            ring[f][q] = wsl[f];
            const float2 wr = __half22float2(wsl[f]);
            rs[f].x += wr.x; rs[f].y += wr.y;
        }
    }

    int i = 0;
    while (i < DS1) {
        #pragma unroll
        for (int p9 = 0; p9 < 9; ++p9) {   // i == p9 (mod 9) whenever body runs
            if (i < DS1) {
                const int dd = ds0 + i + RAD;      // incoming slice
                __half2 wsl[5];
                WSLICE(dd, (dd < DDIM), wsl);
                __half* orec = ob + (size_t)(ds0 + i)*SLH;
                #pragma unroll
                for (int f = 0; f < 5; ++f) {
                    const float2 wa = __half22float2(wsl[f]);
                    rs[f].x += wa.x; rs[f].y += wa.y;      // window [d-4..d+4]
                    *reinterpret_cast<__half2*>(orec + 2*f)
                        = __floats2half2_rn(rs[f].x, rs[f].y);
                    const float2 wd = __half22float2(ring[f][p9]);
                    rs[f].x -= wd.x; rs[f].y -= wd.y;      // drop d-4 (exact)
                    ring[f][(p9+8)%9] = wsl[f];            // keep d+4 (FIXED)
                }
                ++i;
            }
        }
    }
#undef WSLICE
}

// ---------------- P2: H-march over interleaved records + cc + reduce ----------------
// grid: (DDIM/2, HDIM/HT2, C2); block 192 = 96 pairs x 2 d
__global__ __launch_bounds__(192)
void k_hcc2(const __half* __restrict__ buf, double* __restrict__ gacc)
{
    const int tid = threadIdx.x;
    const int p   = tid % RPW;
    const int dl  = tid / RPW;
    const int d   = (int)blockIdx.x*2 + dl;
    const int hs0 = (int)blockIdx.y*HT2;
    const int c   = (int)blockIdx.z;

    // uint view: record = 5 uints (5 x half2); row stride = 480 uints
    const uint* const base =
        reinterpret_cast<const uint*>(buf + ((size_t)c*DDIM + d)*SLH) + p*5;

    __half2 ring[5][9];
    float2  rs[5];
    #pragma unroll
    for (int f = 0; f < 5; ++f) { rs[f].x = 0.f; rs[f].y = 0.f; }
    float acc = 0.f;

#define LOADREC(HH, OK, OUT)                                                  \
    {                                                                         \
        if (OK) {                                                             \
            const uint* rp = base + (size_t)(HH)*480;                         \
            _Pragma("unroll")                                                 \
            for (int f = 0; f < 5; ++f)                                       \
                OUT[f] = __builtin_bit_cast(__half2, rp[f]);                  \
        } else {                                                              \
            _Pragma("unroll")                                                 \
            for (int f = 0; f < 5; ++f)                                       \
                OUT[f] = __builtin_bit_cast(__half2, 0u);                     \
        }                                                                     \
    }

    // warm-up: rows hs0-4 .. hs0+3 fill ring slots 0..7
    #pragma unroll
    for (int q = 0; q < 8; ++q) {
        const int hh = hs0 - RAD + q;
        __half2 rec[5];
        LOADREC(hh, (hh >= 0), rec);
        #pragma unroll
        for (int f = 0; f < 5; ++f) {
            ring[f][q] = rec[f];
            const float2 v = __half22float2(rec[f]);
            rs[f].x += v.x; rs[f].y += v.y;
        }
    }

    int i = 0;
    while (i < HT2) {
        #pragma unroll
        for (int p9 = 0; p9 < 9; ++p9) {   // i == p9 (mod 9) whenever body runs
            if (i < HT2) {
                const int hh = hs0 + i + RAD;
                __half2 rec[5];
                LOADREC(hh, (hh < HDIM), rec);
                float2 S[5];
                #pragma unroll
                for (int f = 0; f < 5; ++f) {
                    const float2 v = __half22float2(rec[f]);
                    rs[f].x += v.x; rs[f].y += v.y;    // full 9^3 sum, row hs0+i
                    S[f] = rs[f];
                    const float2 w = __half22float2(ring[f][p9]);
                    rs[f].x -= w.x; rs[f].y -= w.y;    // drop row -8 (exact)
                    ring[f][(p9+8)%9] = rec[f];        // keep row +4 (FIXED)
                }
                {
                    const float uI = S[0].x*WINV, uJ = S[1].x*WINV;
                    const float cr = S[4].x - uJ*S[0].x;
                    const float Iv = S[2].x - uI*S[0].x;
                    const float Jv = S[3].x - uJ*S[1].x;
                    acc += cr*cr / (Iv*Jv + 1e-5f);
                }
                {
                    const float uI = S[0].y*WINV, uJ = S[1].y*WINV;
                    const float cr = S[4].y - uJ*S[0].y;
                    const float Iv = S[2].y - uI*S[0].y;
                    const float Jv = S[3].y - uJ*S[1].y;
                    acc += cr*cr / (Iv*Jv + 1e-5f);
                }
                ++i;
            }
        }
    }
#undef LOADREC

    // block reduction (3 waves) -> one double atomic per block
    __shared__ float wred[3];
    #pragma unroll
    for (int off = 32; off > 0; off >>= 1) acc += __shfl_down(acc, off);
    if ((tid & 63) == 0) wred[tid >> 6] = acc;
    __syncthreads();
    if (tid == 0) {
        const float sum = wred[0] + wred[1] + wred[2];
        atomicAdd(gacc, (double)sum);
    }
}

__global__ void k_fin(const double* __restrict__ gacc, float* __restrict__ out)
{
    out[0] = (float)(-gacc[0] / (double)((size_t)C2*DDIM*HDIM*WDIM));
}

extern "C" void kernel_launch(void* const* d_in, const int* in_sizes, int n_in,
                              void* d_out, int out_size, void* d_ws, size_t ws_size,
                              hipStream_t stream)
{
    if (n_in < 2) return;
    const float* I = (const float*)d_in[0];
    const float* J = (const float*)d_in[1];
    float* out = (float*)d_out;
    double* gacc = (double*)d_ws;
    __half* buf = (__half*)((char*)d_ws + 256);

    // interleaved WD-summed records: 2*192*224*96 * 20 B = 165.2 MB
    const size_t need = 256 + (size_t)C2*DDIM*SLH*sizeof(__half);
    if (need > ws_size) return;

    hipMemsetAsync(d_ws, 0, 256, stream);   // zero the double accumulator

    dim3 g1(21504/256, DDIM/DS1, C2);        // 84 x 8 x 2 = 1344 blocks
    k_dwp<<<g1, dim3(256,1,1), 0, stream>>>(I, J, buf);

    dim3 g2(DDIM/2, HDIM/HT2, C2);           // 96 x 8 x 2 = 1536 blocks
    k_hcc2<<<g2, dim3(192,1,1), 0, stream>>>(buf, gacc);

    k_fin<<<1,1,0,stream>>>(gacc, out);
}